// Round 9
// baseline (278.066 us; speedup 1.0000x reference)
//
#include <hip/hip_runtime.h>
#include <hip/hip_bf16.h>

typedef __hip_bfloat16 bf16;
typedef unsigned short u16t;
typedef unsigned int u32t;
typedef __attribute__((ext_vector_type(8))) short bf16x8_t;
typedef __attribute__((ext_vector_type(4))) float f32x4_t;

#define DEVI static __device__ __forceinline__

DEVI float u2f(u32t bits) { union { u32t u; float f; } v; v.u = bits; return v.f; }
DEVI float bflo(u32t u) { return u2f((u & 0xffffu) << 16); }
DEVI float bfhi(u32t u) { return u2f(u & 0xffff0000u); }
DEVI float sh2f(short s) { return u2f(((u32t)(u16t)s) << 16); }
DEVI float bf2f(bf16 h) { return __bfloat162float(h); }
DEVI bf16 f2bf(float f) { return __float2bfloat16(f); }
DEVI u16t f2bfbits(float f) {
  bf16 h = __float2bfloat16(f);
  union { bf16 h; u16t u; } v; v.h = h; return v.u;
}

// async global->LDS, 16B per lane. LDS dest must be wave-uniform base + lane*16.
DEVI void gl_lds16(const void* g, void* l) {
  __builtin_amdgcn_global_load_lds(
      (const __attribute__((address_space(1))) unsigned int*)g,
      (__attribute__((address_space(3))) unsigned int*)l, 16, 0, 0);
}

// Problem constants: x (2,8,56,56,128); windows (2,7,7) -> N=98; NW=512
#define TOK   50176
#define NWIN  512
#define NTOK  98
#define NHEAD 4
#define HDIM  32

// ---------------------------------------------------------------------------
// All four weight matrices fp32 -> bf16 in one launch (dest contiguous).
// ---------------------------------------------------------------------------
__global__ __launch_bounds__(256) void cvt4_k(
    const float* __restrict__ a, const float* __restrict__ b,
    const float* __restrict__ c, const float* __restrict__ d,
    bf16* __restrict__ o) {
  int i = blockIdx.x * 256 + threadIdx.x;
  const float* s; int off;
  if (i < 49152)       { s = a; off = 0; }
  else if (i < 65536)  { s = b; off = 49152; }
  else if (i < 131072) { s = c; off = 65536; }
  else                 { s = d; off = 131072; }
  o[i] = f2bf(s[i - off]);
}

// Transposed bias matrix: BmatT[h][j][i] = btab[relidx[i*98+j]*4+h].
// Row-padded to 112 floats so float4 loads at i in [96,112) stay in-bounds.
__global__ __launch_bounds__(256) void bias_k(const float* __restrict__ btab,
                                              const int* __restrict__ relidx,
                                              float* __restrict__ BmatT) {
  int idx = blockIdx.x * 256 + threadIdx.x;
  if (idx < NTOK * NTOK) {
    int i = idx / NTOK, j = idx - i * NTOK;
    int r = relidx[idx] * NHEAD;
#pragma unroll
    for (int h = 0; h < NHEAD; h++)
      BmatT[(size_t)(h * NTOK + j) * 112 + i] = btab[r + h];
  }
}

// ---------------------------------------------------------------------------
// LN1 (fp32 input, token order) + window partition -> bf16
// ---------------------------------------------------------------------------
__global__ __launch_bounds__(256) void ln1_k(
    const float* __restrict__ x, const float* __restrict__ w,
    const float* __restrict__ b, bf16* __restrict__ o)
{
  const int wave = threadIdx.x >> 6, lane = threadIdx.x & 63;
  const int t = blockIdx.x * 4 + wave;
  const int c = lane << 1;
  float2 xv = *(const float2*)(x + (size_t)t * 128 + c);
  float x0 = xv.x, x1 = xv.y;
  float s = x0 + x1, ss = x0 * x0 + x1 * x1;
#pragma unroll
  for (int m = 32; m; m >>= 1) { s += __shfl_xor(s, m); ss += __shfl_xor(ss, m); }
  float mean = s * 0.0078125f;
  float var = ss * 0.0078125f - mean * mean;
  float rstd = rsqrtf(var + 1e-5f);
  float y0 = (x0 - mean) * rstd * w[c]     + b[c];
  float y1 = (x1 - mean) * rstd * w[c + 1] + b[c + 1];
  int wi = t % 56; int r = t / 56;
  int hi_ = r % 56; r /= 56;
  int di = r & 7; int bi = r >> 3;
  int nw = ((bi * 4 + (di >> 1)) * 8 + hi_ / 7) * 8 + wi / 7;
  int n  = ((di & 1) * 7 + hi_ % 7) * 7 + wi % 7;
  u32t ov = ((u32t)f2bfbits(y1) << 16) | (u32t)f2bfbits(y0);
  *(u32t*)((u16t*)o + (size_t)(nw * NTOK + n) * 128 + c) = ov;
}

// ---------------------------------------------------------------------------
// LN2 (bf16 input, token order) -> bf16
// ---------------------------------------------------------------------------
__global__ __launch_bounds__(256) void ln2_k(
    const bf16* __restrict__ x, const float* __restrict__ w,
    const float* __restrict__ b, bf16* __restrict__ o)
{
  const int wave = threadIdx.x >> 6, lane = threadIdx.x & 63;
  const int t = blockIdx.x * 4 + wave;
  const int c = lane << 1;
  u32t u = *(const u32t*)((const u16t*)x + (size_t)t * 128 + c);
  float x0 = bflo(u), x1 = bfhi(u);
  float s = x0 + x1, ss = x0 * x0 + x1 * x1;
#pragma unroll
  for (int m = 32; m; m >>= 1) { s += __shfl_xor(s, m); ss += __shfl_xor(ss, m); }
  float mean = s * 0.0078125f;
  float var = ss * 0.0078125f - mean * mean;
  float rstd = rsqrtf(var + 1e-5f);
  float y0 = (x0 - mean) * rstd * w[c]     + b[c];
  float y1 = (x1 - mean) * rstd * w[c + 1] + b[c + 1];
  u32t ov = ((u32t)f2bfbits(y1) << 16) | (u32t)f2bfbits(y0);
  *(u32t*)((u16t*)o + (size_t)t * 128 + c) = ov;
}

// ---------------------------------------------------------------------------
// MFMA GEMM v2: C[M,N] = A[M,K](bf16) @ W[N,K](bf16)^T + bias(fp32).
// 128x64 tile, K processed in 128-wide chunks (KT chunks, compile-time).
// Weights held in REGISTERS (16 bf16x8 frags/wave per chunk, loaded from
// global — L1/L2 resident, shared by all row-blocks). Only A goes through
// LDS: full 128x128 chunk staged once via global_load_lds width=16 with XOR
// chunk swizzle (slot = chunk ^ (row&15)); 32 MFMAs per wave per barrier-pair.
// MODE 0: +bias -> bf16; 1: +bias+winrev+resX(f32) -> bf16;
// MODE 2: +bias+GELU -> bf16; 3: +bias+resB2(bf16) -> fp32 (coalesced)
// ---------------------------------------------------------------------------
template <int MODE, int KT>   // K = KT*128
__global__ __launch_bounds__(256) void gemm2_k(
    const bf16* __restrict__ A, const bf16* __restrict__ W,
    const float* __restrict__ bias, const float* __restrict__ resX,
    const bf16* __restrict__ resB2, bf16* __restrict__ outB,
    float* __restrict__ outF, int N)
{
  __shared__ __align__(16) short As[128 * 128];   // 32KB
  const int K = KT * 128;
  const int tid = threadIdx.x;
  const int rowBase = blockIdx.y << 7;
  const int colBase = blockIdx.x << 6;
  const int wv = tid >> 6, lane = tid & 63;
  const int q = lane >> 4, r16 = lane & 15;
  const int mB = wv << 5;

  f32x4_t acc[2][4];
#pragma unroll
  for (int i = 0; i < 2; i++)
#pragma unroll
    for (int j = 0; j < 4; j++) acc[i][j] = (f32x4_t){0.f, 0.f, 0.f, 0.f};

#pragma unroll
  for (int kt = 0; kt < KT; kt++) {
    const int kc = kt << 7;
    // B-frags from global (cache-resident weights): nt x ks = 16 frags
    bf16x8_t bfr[4][4];
#pragma unroll
    for (int nt = 0; nt < 4; nt++)
#pragma unroll
      for (int ks = 0; ks < 4; ks++)
        bfr[nt][ks] = *(const bf16x8_t*)((const u16t*)W +
            (size_t)(colBase + (nt << 4) + r16) * K + kc + (ks << 5) + (q << 3));
    // stage A chunk 128x128: 2048 16B-chunks, 8/thread, XOR-swizzled slots
#pragma unroll
    for (int t = 0; t < 8; t++) {
      int f = tid + (t << 8);
      int row = f >> 4, cs = (f & 15) ^ (row & 15);
      gl_lds16((const u16t*)A + (size_t)(rowBase + row) * K + kc + (cs << 3),
               &As[f << 3]);
    }
    __syncthreads();
#pragma unroll
    for (int ks = 0; ks < 4; ks++) {
      bf16x8_t af[2];
#pragma unroll
      for (int mt = 0; mt < 2; mt++) {
        int row = mB + (mt << 4) + r16;
        int slot = ((ks << 2) + q) ^ (row & 15);
        af[mt] = *(const bf16x8_t*)&As[(row << 7) + (slot << 3)];
      }
#pragma unroll
      for (int mt = 0; mt < 2; mt++)
#pragma unroll
        for (int nt = 0; nt < 4; nt++)
          acc[mt][nt] = __builtin_amdgcn_mfma_f32_16x16x32_bf16(
              af[mt], bfr[nt][ks], acc[mt][nt], 0, 0, 0);
    }
    __syncthreads();
  }

  float bv[4];
#pragma unroll
  for (int nt = 0; nt < 4; nt++) bv[nt] = bias[colBase + (nt << 4) + r16];

  if (MODE == 3) {
    // stage fp32 C tile (128x64) into As, then coalesced float4 write-out
    float* Cf = (float*)As;
#pragma unroll
    for (int mt = 0; mt < 2; mt++)
#pragma unroll
      for (int reg = 0; reg < 4; reg++) {
        int lrow = mB + (mt << 4) + (q << 2) + reg;
#pragma unroll
        for (int nt = 0; nt < 4; nt++)
          Cf[(lrow << 6) + (nt << 4) + r16] = acc[mt][nt][reg] + bv[nt];
      }
    __syncthreads();
#pragma unroll
    for (int t = 0; t < 8; t++) {
      int f = tid + (t << 8);
      int row = f >> 4, c4 = (f & 15) << 2;
      size_t ob = (size_t)(rowBase + row) * N + colBase + c4;
      const u16t* rp = (const u16t*)resB2 + ob;
      float4 v;
      v.x = Cf[(row << 6) + c4]     + sh2f(rp[0]);
      v.y = Cf[(row << 6) + c4 + 1] + sh2f(rp[1]);
      v.z = Cf[(row << 6) + c4 + 2] + sh2f(rp[2]);
      v.w = Cf[(row << 6) + c4 + 3] + sh2f(rp[3]);
      *(float4*)(outF + ob) = v;
    }
    return;
  }

  // MODES 0/1/2: stage C bf16 into As, then coalesced write-out.
#pragma unroll
  for (int mt = 0; mt < 2; mt++)
#pragma unroll
    for (int reg = 0; reg < 4; reg++) {
      int lrow = mB + (mt << 4) + (q << 2) + reg;
#pragma unroll
      for (int nt = 0; nt < 4; nt++) {
        float v = acc[mt][nt][reg] + bv[nt];
        if (MODE == 2) v = 0.5f * v * (1.0f + erff(v * 0.70710678118654752f));
        As[(lrow << 6) + (nt << 4) + r16] = (short)f2bfbits(v);
      }
    }
  __syncthreads();
#pragma unroll
  for (int t = 0; t < 4; t++) {
    int f = tid + (t << 8);
    int row = f >> 3, c8 = (f & 7) << 3;
    if (MODE == 1) {
      int grow = rowBase + row;
      int nw = grow / NTOK, n = grow - nw * NTOK;
      int wq = nw & 7, hq = (nw >> 3) & 7, dq = (nw >> 6) & 3, bb = nw >> 8;
      int wr = n % 7; int q7 = n / 7; int hr = q7 % 7, dr = q7 / 7;
      int tt = ((bb * 8 + dq * 2 + dr) * 56 + hq * 7 + hr) * 56 + wq * 7 + wr;
      size_t ob = (size_t)tt * 128 + colBase + c8;
      float4 r0 = *(const float4*)(resX + ob);
      float4 r1 = *(const float4*)(resX + ob + 4);
      const short* cs = &As[(row << 6) + c8];
      u16t pk[8];
      pk[0] = f2bfbits(sh2f(cs[0]) + r0.x); pk[1] = f2bfbits(sh2f(cs[1]) + r0.y);
      pk[2] = f2bfbits(sh2f(cs[2]) + r0.z); pk[3] = f2bfbits(sh2f(cs[3]) + r0.w);
      pk[4] = f2bfbits(sh2f(cs[4]) + r1.x); pk[5] = f2bfbits(sh2f(cs[5]) + r1.y);
      pk[6] = f2bfbits(sh2f(cs[6]) + r1.z); pk[7] = f2bfbits(sh2f(cs[7]) + r1.w);
      *(uint4*)((u16t*)outB + ob) = *(const uint4*)pk;
    } else {
      size_t ob = (size_t)(rowBase + row) * N + colBase + c8;
      *(uint4*)((u16t*)outB + ob) = *(const uint4*)&As[(row << 6) + c8];
    }
  }
}

// ---------------------------------------------------------------------------
// MFMA windowed attention (round-8 structure, best measured: 47 µs).
// ---------------------------------------------------------------------------
#define PSTR 136
__global__ __launch_bounds__(256) void attn_mfma_k(
    const bf16* __restrict__ qkv, const float* __restrict__ BmatT,
    bf16* __restrict__ out)
{
  __shared__ short Vt[32 * PSTR];    // V^T [d][j], zero-padded j>=98
  __shared__ short Ps[112 * PSTR];   // P [i][j] bf16, cols 112..135 zeroed
  const int nw = blockIdx.x, h = blockIdx.y;
  const int tid = threadIdx.x;
  const int wv = tid >> 6, lane = tid & 63;
  const int q = lane >> 4, r16 = lane & 15;
  const float scale = 0.17677669529663687f;  // 32^-0.5

  for (int idx = tid; idx < 32 * 38; idx += 256) {
    int d = idx / 38, j = 98 + idx % 38;
    Vt[d * PSTR + j] = 0;
  }
  for (int idx = tid; idx < 112 * 12; idx += 256) {
    int r = idx / 12, c = (idx % 12) << 1;
    *(u32t*)&Ps[r * PSTR + 112 + c] = 0;
  }
  for (int idx = tid; idx < NTOK * 16; idx += 256) {
    int j = idx >> 4, d2 = (idx & 15) << 1;
    u32t uv = *(const u32t*)((const u16t*)qkv +
                             (size_t)(nw * NTOK + j) * 384 + 256 + h * 32 + d2);
    Vt[d2 * PSTR + j] = (short)(uv & 0xffffu);
    Vt[(d2 + 1) * PSTR + j] = (short)(uv >> 16);
  }
  __syncthreads();

  const int mt0 = wv;
  const bool has2 = (wv + 4) < 7;
  const int mt1 = has2 ? wv + 4 : wv;

  int i0 = mt0 * 16 + r16; if (i0 > NTOK - 1) i0 = NTOK - 1;
  int i1 = mt1 * 16 + r16; if (i1 > NTOK - 1) i1 = NTOK - 1;
  bf16x8_t aq0 = *(const bf16x8_t*)((const u16t*)qkv +
      (size_t)(nw * NTOK + i0) * 384 + h * 32 + (q << 3));
  bf16x8_t aq1 = *(const bf16x8_t*)((const u16t*)qkv +
      (size_t)(nw * NTOK + i1) * 384 + h * 32 + (q << 3));

  f32x4_t sc[2][7];
#pragma unroll
  for (int nt = 0; nt < 7; nt++) {
    int j = (nt << 4) + r16; if (j > NTOK - 1) j = NTOK - 1;
    bf16x8_t bk = *(const bf16x8_t*)((const u16t*)qkv +
        (size_t)(nw * NTOK + j) * 384 + 128 + h * 32 + (q << 3));
    sc[0][nt] = __builtin_amdgcn_mfma_f32_16x16x32_bf16(
        aq0, bk, (f32x4_t){0.f, 0.f, 0.f, 0.f}, 0, 0, 0);
    sc[1][nt] = __builtin_amdgcn_mfma_f32_16x16x32_bf16(
        aq1, bk, (f32x4_t){0.f, 0.f, 0.f, 0.f}, 0, 0, 0);
  }

#pragma unroll
  for (int sel = 0; sel < 2; sel++) {
    if (sel == 1 && !has2) break;
    int mtile = sel ? mt1 : mt0;
    int ibase = mtile * 16 + (q << 2);
    float s[4][7];
#pragma unroll
    for (int nt = 0; nt < 7; nt++) {
      int j = (nt << 4) + r16;
      int jc = j > NTOK - 1 ? NTOK - 1 : j;
      float4 bT = *(const float4*)&BmatT[(size_t)(h * NTOK + jc) * 112 + ibase];
      float bTa[4] = {bT.x, bT.y, bT.z, bT.w};
#pragma unroll
      for (int reg = 0; reg < 4; reg++) {
        int i = ibase + reg;
        float v = sc[sel][nt][reg] * scale;
        s[reg][nt] = (i < NTOK && j < NTOK) ? v + bTa[reg] : -1.0e30f;
      }
    }
#pragma unroll
    for (int reg = 0; reg < 4; reg++) {
      float m = -3.0e38f;
#pragma unroll
      for (int nt = 0; nt < 7; nt++) m = fmaxf(m, s[reg][nt]);
#pragma unroll
      for (int d = 8; d; d >>= 1) m = fmaxf(m, __shfl_xor(m, d));
      float sum = 0.f;
#pragma unroll
      for (int nt = 0; nt < 7; nt++) { s[reg][nt] = __expf(s[reg][nt] - m); sum += s[reg][nt]; }
#pragma unroll
      for (int d = 8; d; d >>= 1) sum += __shfl_xor(sum, d);
      float inv = 1.f / sum;
#pragma unroll
      for (int nt = 0; nt < 7; nt++)
        Ps[(ibase + reg) * PSTR + (nt << 4) + r16] =
            (short)f2bfbits(s[reg][nt] * inv);
    }
    // PV (same-wave LDS RAW, no barrier)
    f32x4_t o0 = {0.f, 0.f, 0.f, 0.f}, o1 = {0.f, 0.f, 0.f, 0.f};
#pragma unroll
    for (int kt = 0; kt < 4; kt++) {
      bf16x8_t ap = *(const bf16x8_t*)&Ps[(mtile * 16 + r16) * PSTR + (kt << 5) + (q << 3)];
      bf16x8_t bv0 = *(const bf16x8_t*)&Vt[r16 * PSTR + (kt << 5) + (q << 3)];
      bf16x8_t bv1 = *(const bf16x8_t*)&Vt[(16 + r16) * PSTR + (kt << 5) + (q << 3)];
      o0 = __builtin_amdgcn_mfma_f32_16x16x32_bf16(ap, bv0, o0, 0, 0, 0);
      o1 = __builtin_amdgcn_mfma_f32_16x16x32_bf16(ap, bv1, o1, 0, 0, 0);
    }
#pragma unroll
    for (int reg = 0; reg < 4; reg++) {
      int i = mtile * 16 + (q << 2) + reg;
      if (i < NTOK) {
        size_t ob = (size_t)(nw * NTOK + i) * 128 + h * 32;
        out[ob + r16] = f2bf(o0[reg]);
        out[ob + 16 + r16] = f2bf(o1[reg]);
      }
    }
  }
}

// ---------------------------------------------------------------------------
extern "C" void kernel_launch(void* const* d_in, const int* in_sizes, int n_in,
                              void* d_out, int out_size, void* d_ws, size_t ws_size,
                              hipStream_t stream) {
  const float* x      = (const float*)d_in[0];
  const float* n1w    = (const float*)d_in[1];
  const float* n1b    = (const float*)d_in[2];
  const float* qkv_w  = (const float*)d_in[3];
  const float* qkv_b  = (const float*)d_in[4];
  const float* btab   = (const float*)d_in[5];
  const float* proj_w = (const float*)d_in[6];
  const float* proj_b = (const float*)d_in[7];
  const float* n2w    = (const float*)d_in[8];
  const float* n2b    = (const float*)d_in[9];
  const float* fc1_w  = (const float*)d_in[10];
  const float* fc1_b  = (const float*)d_in[11];
  const float* fc2_w  = (const float*)d_in[12];
  const float* fc2_b  = (const float*)d_in[13];
  const int*   relidx = (const int*)d_in[14];

  // Layout (A = 50176*128*2 B = 12,845,056):
  //   ws[0, 384K): bf16 weights; ws[384K, ~556K): BmatT fp32
  //   R = ws+1MB: qkv [R, R+3A) -> x2 [R, R+A), xn2 [R+A, R+2A),
  //               hmid [R+2A, +A or +4A per ws_size)
  //   d_out scratch: xw = attn = d_out[0,A)
  const size_t Asz = (size_t)TOK * 128 * 2;
  char* ws = (char*)d_ws;
  bf16* wbf   = (bf16*)ws;
  bf16* qkvw16  = wbf;               // 49152
  bf16* projw16 = wbf + 49152;       // 16384
  bf16* fc1w16  = wbf + 65536;       // 65536
  bf16* fc2w16  = wbf + 131072;      // 65536
  float* BmatT = (float*)(ws + 393216);
  char* R = ws + (1 << 20);
  bf16* xw    = (bf16*)d_out;
  bf16* attn  = (bf16*)d_out;
  bf16* qkv   = (bf16*)R;
  bf16* x2    = (bf16*)R;
  bf16* xn2   = (bf16*)(R + Asz);
  bf16* hmid  = (bf16*)(R + 2 * Asz);
  float* out  = (float*)d_out;
  const bool fullM = ws_size >= ((size_t)(1 << 20) + 6 * Asz);

  // 0. weight conversion + transposed bias matrix
  cvt4_k<<<768, 256, 0, stream>>>(qkv_w, proj_w, fc1_w, fc2_w, wbf);
  bias_k<<<38, 256, 0, stream>>>(btab, relidx, BmatT);
  // 1. LN1 + window partition
  ln1_k<<<TOK / 4, 256, 0, stream>>>(x, n1w, n1b, xw);
  // 2. QKV: (50176,128) @ (384,128)^T
  gemm2_k<0, 1><<<dim3(6, TOK / 128), 256, 0, stream>>>(
      xw, qkvw16, qkv_b, nullptr, nullptr, qkv, nullptr, 384);
  // 3. MFMA windowed attention
  attn_mfma_k<<<dim3(NWIN, NHEAD), 256, 0, stream>>>(qkv, BmatT, attn);
  // 4. proj + window reverse + residual(x fp32) -> x2 bf16 (token order)
  gemm2_k<1, 1><<<dim3(2, TOK / 128), 256, 0, stream>>>(
      attn, projw16, proj_b, x, nullptr, x2, nullptr, 128);
  // 5. LN2
  ln2_k<<<TOK / 4, 256, 0, stream>>>(x2, n2w, n2b, xn2);
  // 6/7. MLP
  if (fullM) {
    gemm2_k<2, 1><<<dim3(8, TOK / 128), 256, 0, stream>>>(
        xn2, fc1w16, fc1_b, nullptr, nullptr, hmid, nullptr, 512);
    gemm2_k<3, 4><<<dim3(2, TOK / 128), 256, 0, stream>>>(
        hmid, fc2w16, fc2_b, nullptr, x2, nullptr, out, 128);
  } else {
    const int MC = TOK / 4;  // 12544 rows per chunk
    for (int c = 0; c < 4; c++) {
      gemm2_k<2, 1><<<dim3(8, MC / 128), 256, 0, stream>>>(
          xn2 + (size_t)c * MC * 128, fc1w16, fc1_b, nullptr, nullptr,
          hmid, nullptr, 512);
      gemm2_k<3, 4><<<dim3(2, MC / 128), 256, 0, stream>>>(
          hmid, fc2w16, fc2_b, nullptr, x2 + (size_t)c * MC * 128,
          nullptr, out + (size_t)c * MC * 128, 128);
    }
  }
}

// Round 10
// 233.475 us; speedup vs baseline: 1.1910x; 1.1910x over previous
//
#include <hip/hip_runtime.h>
#include <hip/hip_bf16.h>

typedef __hip_bfloat16 bf16;
typedef unsigned short u16t;
typedef unsigned int u32t;
typedef __attribute__((ext_vector_type(8))) short bf16x8_t;
typedef __attribute__((ext_vector_type(4))) float f32x4_t;

#define DEVI static __device__ __forceinline__

DEVI float u2f(u32t bits) { union { u32t u; float f; } v; v.u = bits; return v.f; }
DEVI float bflo(u32t u) { return u2f((u & 0xffffu) << 16); }
DEVI float bfhi(u32t u) { return u2f(u & 0xffff0000u); }
DEVI float sh2f(short s) { return u2f(((u32t)(u16t)s) << 16); }
DEVI float bf2f(bf16 h) { return __bfloat162float(h); }
DEVI bf16 f2bf(float f) { return __float2bfloat16(f); }
DEVI u16t f2bfbits(float f) {
  bf16 h = __float2bfloat16(f);
  union { bf16 h; u16t u; } v; v.h = h; return v.u;
}

// async global->LDS, 16B per lane. LDS dest must be wave-uniform base + lane*16.
DEVI void gl_lds16(const void* g, void* l) {
  __builtin_amdgcn_global_load_lds(
      (const __attribute__((address_space(1))) unsigned int*)g,
      (__attribute__((address_space(3))) unsigned int*)l, 16, 0, 0);
}

// Problem constants: x (2,8,56,56,128); windows (2,7,7) -> N=98; NW=512
#define TOK   50176
#define NWIN  512
#define NTOK  98
#define NHEAD 4
#define HDIM  32
#define QSCALE 0.17677669529663687f

// ---------------------------------------------------------------------------
// Weights fp32 -> bf16 (one launch). Q-rows of qkv_w pre-scaled by 32^-0.5.
// ---------------------------------------------------------------------------
__global__ __launch_bounds__(256) void cvt4_k(
    const float* __restrict__ a, const float* __restrict__ b,
    const float* __restrict__ c, const float* __restrict__ d,
    bf16* __restrict__ o) {
  int i = blockIdx.x * 256 + threadIdx.x;
  const float* s; int off;
  if (i < 49152)       { s = a; off = 0; }
  else if (i < 65536)  { s = b; off = 49152; }
  else if (i < 131072) { s = c; off = 65536; }
  else                 { s = d; off = 131072; }
  float v = s[i - off];
  if (i < 16384) v *= QSCALE;     // q-slice of qkv_w
  o[i] = f2bf(v);
}

// Transposed bias matrix BmatT[h][j][i] (row-padded to 112) + scaled qkv bias.
__global__ __launch_bounds__(256) void bias_k(const float* __restrict__ btab,
                                              const int* __restrict__ relidx,
                                              const float* __restrict__ qkv_b,
                                              float* __restrict__ BmatT,
                                              float* __restrict__ bsc) {
  int idx = blockIdx.x * 256 + threadIdx.x;
  if (idx < NTOK * NTOK) {
    int i = idx / NTOK, j = idx - i * NTOK;
    int r = relidx[idx] * NHEAD;
#pragma unroll
    for (int h = 0; h < NHEAD; h++)
      BmatT[(size_t)(h * NTOK + j) * 112 + i] = btab[r + h];
  }
  if (blockIdx.x == 0 && threadIdx.x < 384)
    bsc[threadIdx.x] = qkv_b[threadIdx.x] * (threadIdx.x < 128 ? QSCALE : 1.0f);
}

// ---------------------------------------------------------------------------
// LN1 (fp32 input, token order) + window partition -> bf16
// ---------------------------------------------------------------------------
__global__ __launch_bounds__(256) void ln1_k(
    const float* __restrict__ x, const float* __restrict__ w,
    const float* __restrict__ b, bf16* __restrict__ o)
{
  const int wave = threadIdx.x >> 6, lane = threadIdx.x & 63;
  const int t = blockIdx.x * 4 + wave;
  const int c = lane << 1;
  float2 xv = *(const float2*)(x + (size_t)t * 128 + c);
  float x0 = xv.x, x1 = xv.y;
  float s = x0 + x1, ss = x0 * x0 + x1 * x1;
#pragma unroll
  for (int m = 32; m; m >>= 1) { s += __shfl_xor(s, m); ss += __shfl_xor(ss, m); }
  float mean = s * 0.0078125f;
  float var = ss * 0.0078125f - mean * mean;
  float rstd = rsqrtf(var + 1e-5f);
  float y0 = (x0 - mean) * rstd * w[c]     + b[c];
  float y1 = (x1 - mean) * rstd * w[c + 1] + b[c + 1];
  int wi = t % 56; int r = t / 56;
  int hi_ = r % 56; r /= 56;
  int di = r & 7; int bi = r >> 3;
  int nw = ((bi * 4 + (di >> 1)) * 8 + hi_ / 7) * 8 + wi / 7;
  int n  = ((di & 1) * 7 + hi_ % 7) * 7 + wi % 7;
  u32t ov = ((u32t)f2bfbits(y1) << 16) | (u32t)f2bfbits(y0);
  *(u32t*)((u16t*)o + (size_t)(nw * NTOK + n) * 128 + c) = ov;
}

// window-reverse: grow = nw*98+n -> token index
DEVI int winrev(int grow) {
  int nw = grow / NTOK, n = grow - nw * NTOK;
  int wq = nw & 7, hq = (nw >> 3) & 7, dq = (nw >> 6) & 3, bb = nw >> 8;
  int wr = n % 7; int q7 = n / 7; int hr = q7 % 7, dr = q7 / 7;
  return ((bb * 8 + dq * 2 + dr) * 56 + hq * 7 + hr) * 56 + wq * 7 + wr;
}

// ---------------------------------------------------------------------------
// MFMA GEMM v3: C[M,N] = A[M,K](bf16) @ W[N,K](bf16)^T + bias(fp32).
// 128 x (NT16*16) tile. K in 128-wide chunks; per chunk, A (32KB) and B
// cooperatively staged via global_load_lds width=16 with XOR chunk swizzle
// (slot = chunk ^ (row&15)); ONE barrier-pair per chunk, 8*NT16 MFMAs/wave.
// MODE 0: +bias -> bf16 (NT16=4)
// MODE 1: +bias +winrev +resX(f32) -> x2 bf16 AND fused LN2 -> xn2 (NT16=8)
// MODE 2: +bias +GELU -> bf16 (NT16=4)
// MODE 3: +bias +resB2(bf16) -> fp32 final (NT16=4, KT=4)
// ---------------------------------------------------------------------------
template <int MODE, int NT16, int KT>
__global__ __launch_bounds__(256) void gemm3_k(
    const bf16* __restrict__ A, const bf16* __restrict__ W,
    const float* __restrict__ bias, const float* __restrict__ resX,
    const bf16* __restrict__ resB2, bf16* __restrict__ outB,
    bf16* __restrict__ outB2, float* __restrict__ outF,
    const float* __restrict__ lnw, const float* __restrict__ lnb, int N)
{
  __shared__ __align__(16) short As[128 * 128];          // 32KB
  __shared__ __align__(16) short Bs[NT16 * 16 * 128];
  const int K = KT * 128;
  const int tid = threadIdx.x;
  const int rowBase = blockIdx.y << 7;
  const int colBase = blockIdx.x * (NT16 * 16);
  const int wv = tid >> 6, lane = tid & 63;
  const int q = lane >> 4, r16 = lane & 15;
  const int mB = wv << 5;

  f32x4_t acc[2][NT16];
#pragma unroll
  for (int i = 0; i < 2; i++)
#pragma unroll
    for (int j = 0; j < NT16; j++) acc[i][j] = (f32x4_t){0.f, 0.f, 0.f, 0.f};

#pragma unroll
  for (int kt = 0; kt < KT; kt++) {
    const int kc = kt << 7;
    // stage A chunk 128x128: 2048 chunks, 8/thread
#pragma unroll
    for (int t = 0; t < 8; t++) {
      int f = tid + (t << 8);
      int row = f >> 4, cs = (f & 15) ^ (row & 15);
      gl_lds16((const u16t*)A + (size_t)(rowBase + row) * K + kc + (cs << 3),
               &As[f << 3]);
    }
    // stage B chunk (NT16*16)x128: NT16*256 chunks, NT16/thread
#pragma unroll
    for (int t = 0; t < NT16; t++) {
      int f = tid + (t << 8);
      int row = f >> 4, cs = (f & 15) ^ (row & 15);
      gl_lds16((const u16t*)W + (size_t)(colBase + row) * K + kc + (cs << 3),
               &Bs[f << 3]);
    }
    __syncthreads();
#pragma unroll
    for (int ks = 0; ks < 4; ks++) {
      bf16x8_t af[2], bfr[NT16];
#pragma unroll
      for (int mt = 0; mt < 2; mt++) {
        int row = mB + (mt << 4) + r16;
        int slot = ((ks << 2) + q) ^ (row & 15);
        af[mt] = *(const bf16x8_t*)&As[(row << 7) + (slot << 3)];
      }
#pragma unroll
      for (int nt = 0; nt < NT16; nt++) {
        int row = (nt << 4) + r16;
        int slot = ((ks << 2) + q) ^ (row & 15);
        bfr[nt] = *(const bf16x8_t*)&Bs[(row << 7) + (slot << 3)];
      }
#pragma unroll
      for (int mt = 0; mt < 2; mt++)
#pragma unroll
        for (int nt = 0; nt < NT16; nt++)
          acc[mt][nt] = __builtin_amdgcn_mfma_f32_16x16x32_bf16(
              af[mt], bfr[nt], acc[mt][nt], 0, 0, 0);
    }
    __syncthreads();
  }

  float bv[NT16];
#pragma unroll
  for (int nt = 0; nt < NT16; nt++) bv[nt] = bias[colBase + (nt << 4) + r16];

  if (MODE == 3) {
    // fp32 C tile staged (stride 64 floats), coalesced float4 out + residual
    float* Cf = (float*)As;
#pragma unroll
    for (int mt = 0; mt < 2; mt++)
#pragma unroll
      for (int reg = 0; reg < 4; reg++) {
        int lrow = mB + (mt << 4) + (q << 2) + reg;
#pragma unroll
        for (int nt = 0; nt < NT16; nt++)
          Cf[(lrow << 6) + (nt << 4) + r16] = acc[mt][nt][reg] + bv[nt];
      }
    __syncthreads();
#pragma unroll
    for (int t = 0; t < 8; t++) {
      int f = tid + (t << 8);
      int row = f >> 4, c4 = (f & 15) << 2;
      size_t ob = (size_t)(rowBase + row) * N + colBase + c4;
      const u16t* rp = (const u16t*)resB2 + ob;
      float4 v;
      v.x = Cf[(row << 6) + c4]     + sh2f(rp[0]);
      v.y = Cf[(row << 6) + c4 + 1] + sh2f(rp[1]);
      v.z = Cf[(row << 6) + c4 + 2] + sh2f(rp[2]);
      v.w = Cf[(row << 6) + c4 + 3] + sh2f(rp[3]);
      *(float4*)(outF + ob) = v;
    }
    return;
  }

  if (MODE == 1) {
    // proj (NT16=8, N=128, colBase=0): C+bias -> LDS (stride 128)
#pragma unroll
    for (int mt = 0; mt < 2; mt++)
#pragma unroll
      for (int reg = 0; reg < 4; reg++) {
        int lrow = mB + (mt << 4) + (q << 2) + reg;
#pragma unroll
        for (int nt = 0; nt < NT16; nt++)
          As[(lrow << 7) + (nt << 4) + r16] = (short)f2bfbits(acc[mt][nt][reg] + bv[nt]);
      }
    __syncthreads();
    // residual add (token-addressed), write x2, update LDS with x2
#pragma unroll
    for (int t = 0; t < 8; t++) {
      int f = tid + (t << 8);
      int row = f >> 4, c8 = (f & 15) << 3;
      int tt = winrev(rowBase + row);
      size_t ob = (size_t)tt * 128 + c8;
      float4 r0 = *(const float4*)(resX + ob);
      float4 r1 = *(const float4*)(resX + ob + 4);
      short* cs = &As[(row << 7) + c8];
      u16t pk[8];
      pk[0] = f2bfbits(sh2f(cs[0]) + r0.x); pk[1] = f2bfbits(sh2f(cs[1]) + r0.y);
      pk[2] = f2bfbits(sh2f(cs[2]) + r0.z); pk[3] = f2bfbits(sh2f(cs[3]) + r0.w);
      pk[4] = f2bfbits(sh2f(cs[4]) + r1.x); pk[5] = f2bfbits(sh2f(cs[5]) + r1.y);
      pk[6] = f2bfbits(sh2f(cs[6]) + r1.z); pk[7] = f2bfbits(sh2f(cs[7]) + r1.w);
      *(uint4*)((u16t*)outB + ob) = *(const uint4*)pk;
      *(uint4*)cs = *(const uint4*)pk;
    }
    __syncthreads();
    // fused LN2: one wave per row (32 rows/wave), coalesced u32 LDS reads
    const int c = lane << 1;
    float2 lw = *(const float2*)(lnw + c);
    float2 lb = *(const float2*)(lnb + c);
#pragma unroll 4
    for (int rr = 0; rr < 32; rr++) {
      int row = (wv << 5) + rr;
      u32t u = *(const u32t*)&As[(row << 7) + c];
      float x0 = bflo(u), x1 = bfhi(u);
      float s = x0 + x1, ss = x0 * x0 + x1 * x1;
#pragma unroll
      for (int m = 32; m; m >>= 1) { s += __shfl_xor(s, m); ss += __shfl_xor(ss, m); }
      float mean = s * 0.0078125f;
      float var = ss * 0.0078125f - mean * mean;
      float rstd = rsqrtf(var + 1e-5f);
      float y0 = (x0 - mean) * rstd * lw.x + lb.x;
      float y1 = (x1 - mean) * rstd * lw.y + lb.y;
      int tt = winrev(rowBase + row);
      u32t ov = ((u32t)f2bfbits(y1) << 16) | (u32t)f2bfbits(y0);
      *(u32t*)((u16t*)outB2 + (size_t)tt * 128 + c) = ov;
    }
    return;
  }

  // MODES 0/2: C bf16 staged (stride 64), coalesced uint4 out
#pragma unroll
  for (int mt = 0; mt < 2; mt++)
#pragma unroll
    for (int reg = 0; reg < 4; reg++) {
      int lrow = mB + (mt << 4) + (q << 2) + reg;
#pragma unroll
      for (int nt = 0; nt < NT16; nt++) {
        float v = acc[mt][nt][reg] + bv[nt];
        if (MODE == 2) v = 0.5f * v * (1.0f + erff(v * 0.70710678118654752f));
        As[(lrow << 6) + (nt << 4) + r16] = (short)f2bfbits(v);
      }
    }
  __syncthreads();
#pragma unroll
  for (int t = 0; t < 4; t++) {
    int f = tid + (t << 8);
    int row = f >> 3, c8 = (f & 7) << 3;
    size_t ob = (size_t)(rowBase + row) * N + colBase + c8;
    *(uint4*)((u16t*)outB + ob) = *(const uint4*)&As[(row << 6) + c8];
  }
}

// ---------------------------------------------------------------------------
// MFMA windowed attention (round-8 structure; bias pre-loaded into the QK
// accumulator in C-layout; q pre-scaled at weight conversion).
// ---------------------------------------------------------------------------
#define PSTR 136
__global__ __launch_bounds__(256) void attn_mfma_k(
    const bf16* __restrict__ qkv, const float* __restrict__ BmatT,
    bf16* __restrict__ out)
{
  __shared__ short Vt[32 * PSTR];    // V^T [d][j], zero-padded j>=98
  __shared__ short Ps[112 * PSTR];   // P [i][j] bf16, cols 112..135 zeroed
  const int nw = blockIdx.x, h = blockIdx.y;
  const int tid = threadIdx.x;
  const int wv = tid >> 6, lane = tid & 63;
  const int q = lane >> 4, r16 = lane & 15;

  for (int idx = tid; idx < 32 * 38; idx += 256) {
    int d = idx / 38, j = 98 + idx % 38;
    Vt[d * PSTR + j] = 0;
  }
  for (int idx = tid; idx < 112 * 12; idx += 256) {
    int r = idx / 12, c = (idx % 12) << 1;
    *(u32t*)&Ps[r * PSTR + 112 + c] = 0;
  }
  for (int idx = tid; idx < NTOK * 16; idx += 256) {
    int j = idx >> 4, d2 = (idx & 15) << 1;
    u32t uv = *(const u32t*)((const u16t*)qkv +
                             (size_t)(nw * NTOK + j) * 384 + 256 + h * 32 + d2);
    Vt[d2 * PSTR + j] = (short)(uv & 0xffffu);
    Vt[(d2 + 1) * PSTR + j] = (short)(uv >> 16);
  }
  __syncthreads();

  const int mt0 = wv;
  const bool has2 = (wv + 4) < 7;
  const int mt1 = has2 ? wv + 4 : wv;

  int i0 = mt0 * 16 + r16; if (i0 > NTOK - 1) i0 = NTOK - 1;
  int i1 = mt1 * 16 + r16; if (i1 > NTOK - 1) i1 = NTOK - 1;
  bf16x8_t aq0 = *(const bf16x8_t*)((const u16t*)qkv +
      (size_t)(nw * NTOK + i0) * 384 + h * 32 + (q << 3));
  bf16x8_t aq1 = *(const bf16x8_t*)((const u16t*)qkv +
      (size_t)(nw * NTOK + i1) * 384 + h * 32 + (q << 3));

  f32x4_t sc[2][7];
#pragma unroll
  for (int nt = 0; nt < 7; nt++) {
    int j = (nt << 4) + r16; if (j > NTOK - 1) j = NTOK - 1;
    const float* bRow = &BmatT[(size_t)(h * NTOK + j) * 112];
    bf16x8_t bk = *(const bf16x8_t*)((const u16t*)qkv +
        (size_t)(nw * NTOK + j) * 384 + 128 + h * 32 + (q << 3));
    f32x4_t b0 = *(const f32x4_t*)&bRow[mt0 * 16 + (q << 2)];
    f32x4_t b1 = *(const f32x4_t*)&bRow[mt1 * 16 + (q << 2)];
    sc[0][nt] = __builtin_amdgcn_mfma_f32_16x16x32_bf16(aq0, bk, b0, 0, 0, 0);
    sc[1][nt] = __builtin_amdgcn_mfma_f32_16x16x32_bf16(aq1, bk, b1, 0, 0, 0);
  }

#pragma unroll
  for (int sel = 0; sel < 2; sel++) {
    if (sel == 1 && !has2) break;
    int mtile = sel ? mt1 : mt0;
    int ibase = mtile * 16 + (q << 2);
    float s[4][7];
#pragma unroll
    for (int nt = 0; nt < 7; nt++) {
      int j = (nt << 4) + r16;
#pragma unroll
      for (int reg = 0; reg < 4; reg++) {
        int i = ibase + reg;
        s[reg][nt] = (i < NTOK && j < NTOK) ? sc[sel][nt][reg] : -1.0e30f;
      }
    }
#pragma unroll
    for (int reg = 0; reg < 4; reg++) {
      float m = -3.0e38f;
#pragma unroll
      for (int nt = 0; nt < 7; nt++) m = fmaxf(m, s[reg][nt]);
#pragma unroll
      for (int d = 8; d; d >>= 1) m = fmaxf(m, __shfl_xor(m, d));
      float sum = 0.f;
#pragma unroll
      for (int nt = 0; nt < 7; nt++) { s[reg][nt] = __expf(s[reg][nt] - m); sum += s[reg][nt]; }
#pragma unroll
      for (int d = 8; d; d >>= 1) sum += __shfl_xor(sum, d);
      float inv = 1.f / sum;
#pragma unroll
      for (int nt = 0; nt < 7; nt++)
        Ps[(ibase + reg) * PSTR + (nt << 4) + r16] =
            (short)f2bfbits(s[reg][nt] * inv);
    }
    // PV (same-wave LDS RAW, no barrier)
    f32x4_t o0 = {0.f, 0.f, 0.f, 0.f}, o1 = {0.f, 0.f, 0.f, 0.f};
#pragma unroll
    for (int kt = 0; kt < 4; kt++) {
      bf16x8_t ap = *(const bf16x8_t*)&Ps[(mtile * 16 + r16) * PSTR + (kt << 5) + (q << 3)];
      bf16x8_t bv0 = *(const bf16x8_t*)&Vt[r16 * PSTR + (kt << 5) + (q << 3)];
      bf16x8_t bv1 = *(const bf16x8_t*)&Vt[(16 + r16) * PSTR + (kt << 5) + (q << 3)];
      o0 = __builtin_amdgcn_mfma_f32_16x16x32_bf16(ap, bv0, o0, 0, 0, 0);
      o1 = __builtin_amdgcn_mfma_f32_16x16x32_bf16(ap, bv1, o1, 0, 0, 0);
    }
#pragma unroll
    for (int reg = 0; reg < 4; reg++) {
      int i = mtile * 16 + (q << 2) + reg;
      if (i < NTOK) {
        size_t ob = (size_t)(nw * NTOK + i) * 128 + h * 32;
        out[ob + r16] = f2bf(o0[reg]);
        out[ob + 16 + r16] = f2bf(o1[reg]);
      }
    }
  }
}

// ---------------------------------------------------------------------------
extern "C" void kernel_launch(void* const* d_in, const int* in_sizes, int n_in,
                              void* d_out, int out_size, void* d_ws, size_t ws_size,
                              hipStream_t stream) {
  const float* x      = (const float*)d_in[0];
  const float* n1w    = (const float*)d_in[1];
  const float* n1b    = (const float*)d_in[2];
  const float* qkv_w  = (const float*)d_in[3];
  const float* qkv_b  = (const float*)d_in[4];
  const float* btab   = (const float*)d_in[5];
  const float* proj_w = (const float*)d_in[6];
  const float* proj_b = (const float*)d_in[7];
  const float* n2w    = (const float*)d_in[8];
  const float* n2b    = (const float*)d_in[9];
  const float* fc1_w  = (const float*)d_in[10];
  const float* fc1_b  = (const float*)d_in[11];
  const float* fc2_w  = (const float*)d_in[12];
  const float* fc2_b  = (const float*)d_in[13];
  const int*   relidx = (const int*)d_in[14];

  // Layout (A = 50176*128*2 B = 12,845,056):
  //   ws[0,384K): bf16 weights; ws[384K,+176K): BmatT; then bscaled (1.5KB)
  //   R = ws+1MB: qkv [R,R+3A) -> x2 [R,R+A), xn2 [R+A,R+2A),
  //               hmid [R+2A, +A or +4A per ws_size)
  //   d_out scratch: xw = attn = d_out[0,A)
  const size_t Asz = (size_t)TOK * 128 * 2;
  char* ws = (char*)d_ws;
  bf16* wbf   = (bf16*)ws;
  bf16* qkvw16  = wbf;               // 49152
  bf16* projw16 = wbf + 49152;       // 16384
  bf16* fc1w16  = wbf + 65536;       // 65536
  bf16* fc2w16  = wbf + 131072;      // 65536
  float* BmatT = (float*)(ws + 393216);            // 4*98*112 fp32 = 175,616 B
  float* bsc   = (float*)(ws + 393216 + 175616);   // 384 fp32
  char* R = ws + (1 << 20);
  bf16* xw    = (bf16*)d_out;
  bf16* attn  = (bf16*)d_out;
  bf16* qkv   = (bf16*)R;
  bf16* x2    = (bf16*)R;
  bf16* xn2   = (bf16*)(R + Asz);
  bf16* hmid  = (bf16*)(R + 2 * Asz);
  float* out  = (float*)d_out;
  const bool fullM = ws_size >= ((size_t)(1 << 20) + 6 * Asz);

  // 0. weight conversion (q pre-scaled) + bias matrix + scaled qkv bias
  cvt4_k<<<768, 256, 0, stream>>>(qkv_w, proj_w, fc1_w, fc2_w, wbf);
  bias_k<<<38, 256, 0, stream>>>(btab, relidx, qkv_b, BmatT, bsc);
  // 1. LN1 + window partition
  ln1_k<<<TOK / 4, 256, 0, stream>>>(x, n1w, n1b, xw);
  // 2. QKV: (50176,128) @ (384,128)^T
  gemm3_k<0, 4, 1><<<dim3(6, TOK / 128), 256, 0, stream>>>(
      xw, qkvw16, bsc, nullptr, nullptr, qkv, nullptr, nullptr,
      nullptr, nullptr, 384);
  // 3. MFMA windowed attention
  attn_mfma_k<<<dim3(NWIN, NHEAD), 256, 0, stream>>>(qkv, BmatT, attn);
  // 4. proj + window reverse + residual + fused LN2 -> x2, xn2
  gemm3_k<1, 8, 1><<<dim3(1, TOK / 128), 256, 0, stream>>>(
      attn, projw16, proj_b, x, nullptr, x2, xn2, nullptr, n2w, n2b, 128);
  // 5/6. MLP
  if (fullM) {
    gemm3_k<2, 4, 1><<<dim3(8, TOK / 128), 256, 0, stream>>>(
        xn2, fc1w16, fc1_b, nullptr, nullptr, hmid, nullptr, nullptr,
        nullptr, nullptr, 512);
    gemm3_k<3, 4, 4><<<dim3(2, TOK / 128), 256, 0, stream>>>(
        hmid, fc2w16, fc2_b, nullptr, x2, nullptr, nullptr, out,
        nullptr, nullptr, 128);
  } else {
    const int MC = TOK / 4;  // 12544 rows per chunk
    for (int c = 0; c < 4; c++) {
      gemm3_k<2, 4, 1><<<dim3(8, MC / 128), 256, 0, stream>>>(
          xn2 + (size_t)c * MC * 128, fc1w16, fc1_b, nullptr, nullptr,
          hmid, nullptr, nullptr, nullptr, nullptr, 512);
      gemm3_k<3, 4, 4><<<dim3(2, MC / 128), 256, 0, stream>>>(
          hmid, fc2w16, fc2_b, nullptr, x2 + (size_t)c * MC * 128,
          nullptr, nullptr, out + (size_t)c * MC * 128, nullptr, nullptr, 128);
    }
  }
}